// Round 1
// baseline (796.335 us; speedup 1.0000x reference)
//
#include <hip/hip_runtime.h>
#include <hip/hip_bf16.h>

// XCA-style channel attention, B=8 DIM=512 M=8192 H=8 HC=64.
// Pipeline: k0 cvt weights->bf16 | k1 qkv GEMM (+bias, norms) | k2 S=q.kT partials
//           k3 softmax + Wb = w_po@blockdiag(attn) | k4 out = Wb@v + b_po.

#define NB 8
#define DIM 512
#define MM 8192
#define NH 8
#define HC 64

typedef __attribute__((ext_vector_type(8))) short short8;
typedef __attribute__((ext_vector_type(4))) float floatx4;
typedef __attribute__((ext_vector_type(4))) unsigned short ushort4v;

__device__ __forceinline__ floatx4 mfma16(short8 a, short8 b, floatx4 c){
    return __builtin_amdgcn_mfma_f32_16x16x32_bf16(a, b, c, 0, 0, 0);
}
__device__ __forceinline__ unsigned short f2bf(float f){
    return __builtin_bit_cast(unsigned short, (__bf16)f);   // RNE hw cvt on gfx950
}

// ---------------- k0: convert w_kv, w_q, w_po to bf16 ----------------
__global__ void k0_cvt(const float* __restrict__ wkv, const float* __restrict__ wq,
                       const float* __restrict__ wpo, unsigned short* __restrict__ wbf)
{
    const int n0 = 1024*512, n1 = n0 + 512*512, n2 = n1 + 512*512;
    for (int i = blockIdx.x*blockDim.x + threadIdx.x; i < n2; i += gridDim.x*blockDim.x){
        float v;
        if (i < n0) v = wkv[i];
        else if (i < n1) v = wq[i - n0];
        else v = wpo[i - n1];
        wbf[i] = f2bf(v);
    }
}

// ---------------- k1: kv = w_kv@desc + b_kv ; q = w_q@seg + b_q -------------
// grid (64 m-blocks of 128, 6 o-blocks of 256, B). 512 thr = 8 waves (4 o x 2 m),
// each wave 64x64 via 4x4 frags of 16x16x32 MFMA. A (weights bf16) direct 16B loads;
// B (f32 activations) 8 strided scalar loads per frag (coalesced across lanes) + cvt.
// o-blocks 0-1 -> k rows 0..511 | 2-3 -> v rows 512..1023 (stored transposed [m][c])
// | 4-5 -> q. k,q also accumulate row sum-of-squares into nsq (atomic).
__launch_bounds__(512)
__global__ void k1_qkv(const float* __restrict__ desc, const float* __restrict__ seg,
                       const unsigned short* __restrict__ wbf,
                       const float* __restrict__ bkv, const float* __restrict__ bq,
                       unsigned short* __restrict__ qbf, unsigned short* __restrict__ kbf,
                       unsigned short* __restrict__ vt, float* __restrict__ nsq)
{
    const int mb = blockIdx.x;
    const int ob = blockIdx.y;
    const int b  = blockIdx.z;
    const int tid = threadIdx.x;
    const int lane = tid & 63;
    const int w  = tid >> 6;
    const int wo = w >> 1;        // 0..3
    const int wm = w & 1;         // 0..1
    const int l15 = lane & 15;
    const int lg  = lane >> 4;

    const int oBase = ob * 256;
    const bool isQ = (ob >= 4);
    const int wRow0 = isQ ? (oBase - 1024) : oBase;     // row in weight matrix
    const unsigned short* Wp = isQ ? (wbf + 1024*512) : wbf;
    const float* X = (isQ ? seg : desc) + (size_t)b * DIM * MM;
    const float* bias = isQ ? bq : bkv;

    const int m0 = mb*128 + wm*64;
    const unsigned short* aP = Wp + (size_t)(wRow0 + wo*64 + l15) * DIM + lg*8;
    const float* xP = X + (size_t)(lg*8) * MM + m0 + l15;

    floatx4 acc[4][4] = {};

    for (int k0 = 0; k0 < DIM; k0 += 32){
        short8 a[4];
        #pragma unroll
        for (int rt = 0; rt < 4; ++rt)
            a[rt] = *(const short8*)(aP + (size_t)rt*16*DIM + k0);
        #pragma unroll
        for (int ct = 0; ct < 4; ++ct){
            const float* xc = xP + (size_t)k0 * MM + ct*16;
            short8 xb;
            #pragma unroll
            for (int e = 0; e < 8; ++e)
                xb[e] = (short)f2bf(xc[(size_t)e * MM]);
            #pragma unroll
            for (int rt = 0; rt < 4; ++rt)
                acc[rt][ct] = mfma16(a[rt], xb, acc[rt][ct]);
        }
    }

    // bias
    #pragma unroll
    for (int rt = 0; rt < 4; ++rt){
        #pragma unroll
        for (int r = 0; r < 4; ++r){
            const float brow = bias[wRow0 + wo*64 + rt*16 + lg*4 + r];
            #pragma unroll
            for (int ct = 0; ct < 4; ++ct) acc[rt][ct][r] += brow;
        }
    }

    if (ob < 2 || isQ){
        unsigned short* dst = isQ ? qbf : kbf;
        const int nBase = b*1024 + (isQ ? 512 : 0);
        #pragma unroll
        for (int rt = 0; rt < 4; ++rt){
            const int chBase = wRow0 + wo*64 + rt*16 + lg*4;   // 0..511 local
            #pragma unroll
            for (int r = 0; r < 4; ++r){
                const int ch = chBase + r;
                unsigned short* o = dst + ((size_t)b*DIM + ch)*MM + m0;
                float t = 0.f;
                #pragma unroll
                for (int ct = 0; ct < 4; ++ct){
                    const float v = acc[rt][ct][r];
                    t += v*v;
                    o[ct*16 + l15] = f2bf(v);
                }
                t += __shfl_xor(t, 1);
                t += __shfl_xor(t, 2);
                t += __shfl_xor(t, 4);
                t += __shfl_xor(t, 8);
                if (l15 == 0) atomicAdd(&nsq[nBase + ch], t);
            }
        }
    } else {
        // v -> vt[b][m][c]
        #pragma unroll
        for (int rt = 0; rt < 4; ++rt){
            const int c0 = (oBase - 512) + wo*64 + rt*16 + lg*4;
            #pragma unroll
            for (int ct = 0; ct < 4; ++ct){
                const int m = m0 + ct*16 + l15;
                ushort4v pk;
                #pragma unroll
                for (int r = 0; r < 4; ++r) pk[r] = f2bf(acc[rt][ct][r]);
                *(ushort4v*)(vt + ((size_t)b*MM + m)*DIM + c0) = pk;
            }
        }
    }
}

// ---------------- k2: S partials, S[b,h] = q_h @ k_h^T over m ----------------
// grid (64 bh, 8 m-chunks of 1024); 4 waves each own a 32x32 quadrant, full chunk-K.
__launch_bounds__(256)
__global__ void k2_scores(const unsigned short* __restrict__ qbf,
                          const unsigned short* __restrict__ kbf,
                          float* __restrict__ Sp)
{
    const int bh = blockIdx.x;
    const int ms = blockIdx.y;
    const int b = bh >> 3, h = bh & 7;
    const int tid = threadIdx.x;
    const int lane = tid & 63;
    const int w = tid >> 6;
    const int wr = w >> 1, wc = w & 1;
    const int l15 = lane & 15, lg = lane >> 4;

    const unsigned short* qA = qbf + ((size_t)b*DIM + h*HC + wr*32 + l15)*MM + lg*8;
    const unsigned short* kB = kbf + ((size_t)b*DIM + h*HC + wc*32 + l15)*MM + lg*8;

    floatx4 acc[2][2] = {};
    const int kEnd = ms*1024 + 1024;
    for (int k0 = ms*1024; k0 < kEnd; k0 += 32){
        const short8 a0 = *(const short8*)(qA + k0);
        const short8 a1 = *(const short8*)(qA + (size_t)16*MM + k0);
        const short8 b0 = *(const short8*)(kB + k0);
        const short8 b1 = *(const short8*)(kB + (size_t)16*MM + k0);
        acc[0][0] = mfma16(a0, b0, acc[0][0]);
        acc[0][1] = mfma16(a0, b1, acc[0][1]);
        acc[1][0] = mfma16(a1, b0, acc[1][0]);
        acc[1][1] = mfma16(a1, b1, acc[1][1]);
    }
    float* sp = Sp + ((size_t)bh*8 + ms)*4096;
    #pragma unroll
    for (int rt = 0; rt < 2; ++rt)
        #pragma unroll
        for (int ct = 0; ct < 2; ++ct)
            #pragma unroll
            for (int r = 0; r < 4; ++r)
                sp[(wr*32 + rt*16 + lg*4 + r)*64 + wc*32 + ct*16 + l15] = acc[rt][ct][r];
}

// ------- k3: reduce partials, normalize by norms*temp, softmax, Wb build -------
// grid 64 (b,h); 512 thr. Wb[b][o][h*64+d] = sum_c wpo[o][h*64+c] * attn[c][d].
__launch_bounds__(512)
__global__ void k3_attn_w(const float* __restrict__ Sp, const float* __restrict__ nsq,
                          const float* __restrict__ temperature,
                          const unsigned short* __restrict__ wpoBf,
                          unsigned short* __restrict__ Wb)
{
    __shared__ float S[4096];
    __shared__ float rnq[64], rnk[64];
    __shared__ unsigned short Pt[4096];   // attn transposed [d][c], bf16
    const int bh = blockIdx.x;
    const int b = bh >> 3, h = bh & 7;
    const int tid = threadIdx.x;

    for (int e = tid; e < 4096; e += 512){
        float s = 0.f;
        #pragma unroll
        for (int msi = 0; msi < 8; ++msi) s += Sp[((size_t)bh*8 + msi)*4096 + e];
        S[e] = s;
    }
    if (tid < 64){
        rnk[tid] = 1.f / fmaxf(sqrtf(fmaxf(nsq[b*1024 + h*HC + tid], 0.f)), 1e-12f);
        rnq[tid] = 1.f / fmaxf(sqrtf(fmaxf(nsq[b*1024 + 512 + h*HC + tid], 0.f)), 1e-12f);
    }
    __syncthreads();
    if (tid < 64){
        const int c = tid;
        const float sc = temperature[h] * rnq[c];
        float mx = -1e30f;
        for (int d = 0; d < 64; ++d)
            mx = fmaxf(mx, S[c*64 + d] * sc * rnk[d]);
        float sum = 0.f;
        for (int d = 0; d < 64; ++d){
            const float p = __expf(S[c*64 + d] * sc * rnk[d] - mx);
            S[c*64 + d] = p;
            sum += p;
        }
        const float rs = 1.f / sum;
        for (int d = 0; d < 64; ++d)
            Pt[d*64 + c] = f2bf(S[c*64 + d] * rs);
    }
    __syncthreads();

    const int lane = tid & 63, w = tid >> 6;   // wave w -> output rows w*64..+63
    const int l15 = lane & 15, lg = lane >> 4;
    floatx4 acc[4][4] = {};
    #pragma unroll
    for (int ks = 0; ks < 2; ++ks){
        short8 pb[4];
        #pragma unroll
        for (int ct = 0; ct < 4; ++ct)
            pb[ct] = *(const short8*)(Pt + (ct*16 + l15)*64 + ks*32 + lg*8);
        #pragma unroll
        for (int rt = 0; rt < 4; ++rt){
            const int o = w*64 + rt*16 + l15;
            const short8 a = *(const short8*)(wpoBf + (size_t)o*DIM + h*HC + ks*32 + lg*8);
            #pragma unroll
            for (int ct = 0; ct < 4; ++ct)
                acc[rt][ct] = mfma16(a, pb[ct], acc[rt][ct]);
        }
    }
    #pragma unroll
    for (int rt = 0; rt < 4; ++rt){
        const int o = w*64 + rt*16 + lg*4;
        #pragma unroll
        for (int ct = 0; ct < 4; ++ct){
            const int d = ct*16 + l15;
            #pragma unroll
            for (int r = 0; r < 4; ++r)
                Wb[((size_t)b*DIM + o + r)*DIM + h*HC + d] = f2bf(acc[rt][ct][r]);
        }
    }
}

// ---------------- k4: out[b] = Wb[b] @ v[b] + b_po ----------------
// grid (64 m-blocks of 128, 2 o-blocks of 256, B); 8 waves (4 o x 2 m), 64x64 each.
__launch_bounds__(512)
__global__ void k4_out(const unsigned short* __restrict__ Wb,
                       const unsigned short* __restrict__ vt,
                       const float* __restrict__ bpo,
                       float* __restrict__ out)
{
    const int mb = blockIdx.x;
    const int ob = blockIdx.y;
    const int b  = blockIdx.z;
    const int tid = threadIdx.x;
    const int lane = tid & 63, w = tid >> 6;
    const int wo = w >> 1, wm = w & 1;
    const int l15 = lane & 15, lg = lane >> 4;

    const unsigned short* aP = Wb + ((size_t)b*DIM + ob*256 + wo*64 + l15)*DIM + lg*8;
    const unsigned short* bP = vt + ((size_t)b*MM + mb*128 + wm*64 + l15)*DIM + lg*8;

    floatx4 acc[4][4] = {};
    for (int k0 = 0; k0 < DIM; k0 += 32){
        short8 a[4], bb[4];
        #pragma unroll
        for (int rt = 0; rt < 4; ++rt) a[rt] = *(const short8*)(aP + (size_t)rt*16*DIM + k0);
        #pragma unroll
        for (int ct = 0; ct < 4; ++ct) bb[ct] = *(const short8*)(bP + (size_t)ct*16*DIM + k0);
        #pragma unroll
        for (int rt = 0; rt < 4; ++rt)
            #pragma unroll
            for (int ct = 0; ct < 4; ++ct)
                acc[rt][ct] = mfma16(a[rt], bb[ct], acc[rt][ct]);
    }
    #pragma unroll
    for (int rt = 0; rt < 4; ++rt){
        #pragma unroll
        for (int r = 0; r < 4; ++r){
            const int o = ob*256 + wo*64 + rt*16 + lg*4 + r;
            const float bv = bpo[o];
            #pragma unroll
            for (int ct = 0; ct < 4; ++ct){
                const int m = mb*128 + wm*64 + ct*16 + l15;
                out[((size_t)b*DIM + o)*MM + m] = acc[rt][ct][r] + bv;
            }
        }
    }
}

extern "C" void kernel_launch(void* const* d_in, const int* in_sizes, int n_in,
                              void* d_out, int out_size, void* d_ws, size_t ws_size,
                              hipStream_t stream)
{
    const float* desc = (const float*)d_in[0];
    const float* seg  = (const float*)d_in[1];
    const float* wkv  = (const float*)d_in[2];
    const float* bkv  = (const float*)d_in[3];
    const float* wq   = (const float*)d_in[4];
    const float* bq   = (const float*)d_in[5];
    const float* wpo  = (const float*)d_in[6];
    const float* bpo  = (const float*)d_in[7];
    const float* temp = (const float*)d_in[8];
    float* out = (float*)d_out;

    char* ws = (char*)d_ws;
    size_t off = 0;
    auto wsAlloc = [&](size_t bytes) -> void* {
        void* p = ws + off;
        off += (bytes + 255) & ~(size_t)255;
        return p;
    };
    unsigned short* wbf = (unsigned short*)wsAlloc((size_t)(1024*512 + 512*512 + 512*512) * 2);
    unsigned short* qbf = (unsigned short*)wsAlloc((size_t)NB*DIM*MM*2);
    unsigned short* kbf = (unsigned short*)wsAlloc((size_t)NB*DIM*MM*2);
    unsigned short* vt  = (unsigned short*)wsAlloc((size_t)NB*MM*DIM*2);
    float* Sp  = (float*)wsAlloc((size_t)64*8*4096*4);
    float* nsq = (float*)wsAlloc((size_t)NB*1024*4);
    unsigned short* Wb = (unsigned short*)wsAlloc((size_t)NB*DIM*DIM*2);
    if (off > ws_size) return;   // workspace too small: fail loudly (wrong output)

    hipMemsetAsync(nsq, 0, (size_t)NB*1024*4, stream);
    k0_cvt<<<dim3(512), dim3(256), 0, stream>>>(wkv, wq, wpo, wbf);
    k1_qkv<<<dim3(64, 6, NB), dim3(512), 0, stream>>>(desc, seg, wbf, bkv, bq, qbf, kbf, vt, nsq);
    k2_scores<<<dim3(64, 8), dim3(256), 0, stream>>>(qbf, kbf, Sp);
    k3_attn_w<<<dim3(64), dim3(512), 0, stream>>>(Sp, nsq, temp, wbf + 1024*512 + 512*512, Wb);
    k4_out<<<dim3(64, 2, NB), dim3(512), 0, stream>>>(Wb, vt, bpo, out);
}